// Round 6
// baseline (157.922 us; speedup 1.0000x reference)
//
#include <hip/hip_runtime.h>
#include <hip/hip_bf16.h>

#define NB 8
#define NC 512
#define NO 64
#define NH 64
#define NW 64
#define NHW 4096

typedef __attribute__((ext_vector_type(8))) short bf16x8;
typedef __attribute__((ext_vector_type(4))) float f32x4;

__device__ __forceinline__ void gload16(const void* g, void* l) {
    __builtin_amdgcn_global_load_lds(
        (const __attribute__((address_space(1))) void*)g,
        (__attribute__((address_space(3))) void*)l, 16, 0, 0);
}

__device__ __forceinline__ short f2bf_bits(float f) {
    __hip_bfloat16 h = __float2bfloat16(f);
    short s; __builtin_memcpy(&s, &h, 2); return s;
}
__device__ __forceinline__ float bfbits_to_f(short s) {
    unsigned int u = ((unsigned int)(unsigned short)s) << 16;
    float f; __builtin_memcpy(&f, &u, 4); return f;
}

// K0a: pack Wq|Wk|Wv -> Wbf[640][512] bf16, biases -> bias_all[640] f32
__global__ __launch_bounds__(256) void pack_w(
    const float* __restrict__ Wq, const float* __restrict__ bq,
    const float* __restrict__ Wk, const float* __restrict__ bk,
    const float* __restrict__ Wv, const float* __restrict__ bv,
    __hip_bfloat16* __restrict__ Wbf, float* __restrict__ bias_all)
{
    const int row = blockIdx.x;
    const int t = threadIdx.x;
    const float* src; float bias;
    if (row < 64)       { src = Wq + row*NC;        bias = bq[row]; }
    else if (row < 128) { src = Wk + (row-64)*NC;   bias = bk[row-64]; }
    else                { src = Wv + (row-128)*NC;  bias = bv[row-128]; }
    for (int i = t; i < NC; i += 256)
        Wbf[(size_t)row*NC + i] = __float2bfloat16(src[i]);
    if (t == 0) bias_all[row] = bias;
}

// K0b: x[b][c][hw] f32 -> xt[b][hw][c] bf16 (LDS tile transpose)
__global__ __launch_bounds__(256) void transpose_x(
    const float* __restrict__ x, __hip_bfloat16* __restrict__ xt)
{
    __shared__ float tile[64][65];
    const int c0  = blockIdx.x * 64;
    const int hw0 = blockIdx.y * 64;
    const int b   = blockIdx.z;
    const int t = threadIdx.x;
    const int col = t & 63, r4 = t >> 6;
    #pragma unroll
    for (int s = 0; s < 16; ++s) {
        int cr = s*4 + r4;
        tile[cr][col] = x[((size_t)b*NC + c0 + cr)*NHW + hw0 + col];
    }
    __syncthreads();
    #pragma unroll
    for (int s = 0; s < 16; ++s) {
        int wr = s*4 + r4;
        xt[((size_t)b*NHW + hw0 + wr)*NC + c0 + col] = __float2bfloat16(tile[col][wr]);
    }
}

// K1: MFMA QKV projection, double-buffered (1 barrier per K-step).
// A = Wbf [o][c], B = xt[b][hw][c] (both k-contiguous, XOR source pre-swizzle).
__global__ __launch_bounds__(256) void qkv_mfma(
    const __hip_bfloat16* __restrict__ xt, const __hip_bfloat16* __restrict__ Wbf,
    const float* __restrict__ bias_all,
    __hip_bfloat16* __restrict__ qb, __hip_bfloat16* __restrict__ kb,
    __hip_bfloat16* __restrict__ vb)
{
    __shared__ __align__(16) char As[2][16384];   // [row 128][k 64] bf16
    __shared__ __align__(16) char Bs[2][16384];
    const int t = threadIdx.x;
    const int lane = t & 63;
    const int wv = t >> 6;
    const int wm = wv >> 1, wn = wv & 1;
    const int fr = lane & 15, fg = lane >> 4;
    const int hw0 = blockIdx.x * 128;
    const int o0  = blockIdx.y * 128;
    const int b   = blockIdx.z;
    const __hip_bfloat16* xtb = xt + (size_t)b * NHW * NC;

#define STAGE(ksrc, buf)                                                    \
    {                                                                       \
        _Pragma("unroll")                                                   \
        for (int s = 0; s < 4; ++s) {                                       \
            int linear = s*256 + t;                                         \
            int row = linear >> 3, g = linear & 7;                          \
            int gk = (g ^ (row & 7)) * 8;                                   \
            gload16(Wbf + (size_t)(o0 + row)*NC + (ksrc)*64 + gk,           \
                    As[buf] + linear*16);                                   \
            gload16(xtb + (size_t)(hw0 + row)*NC + (ksrc)*64 + gk,          \
                    Bs[buf] + linear*16);                                   \
        }                                                                   \
    }

    STAGE(0, 0);
    __syncthreads();

    f32x4 acc[4][4] = {};

    for (int ks = 0; ks < 8; ++ks) {
        const int cur = ks & 1, nxt = cur ^ 1;
        if (ks < 7) STAGE(ks+1, nxt);
        #pragma unroll
        for (int kk = 0; kk < 2; ++kk) {
            const int gl = kk*4 + fg;
            bf16x8 af[4], bfr[4];
            #pragma unroll
            for (int mf = 0; mf < 4; ++mf) {
                int r = wm*64 + mf*16 + fr;
                af[mf] = *(const bf16x8*)(As[cur] + r*128 + ((gl ^ (r & 7)) << 4));
            }
            #pragma unroll
            for (int nf = 0; nf < 4; ++nf) {
                int c = wn*64 + nf*16 + fr;
                bfr[nf] = *(const bf16x8*)(Bs[cur] + c*128 + ((gl ^ (c & 7)) << 4));
            }
            #pragma unroll
            for (int mf = 0; mf < 4; ++mf)
                #pragma unroll
                for (int nf = 0; nf < 4; ++nf)
                    acc[mf][nf] = __builtin_amdgcn_mfma_f32_16x16x32_bf16(
                        af[mf], bfr[nf], acc[mf][nf], 0, 0, 0);
        }
        if (ks < 7) __syncthreads();   // drains this iter's STAGE after compute
    }
#undef STAGE

    // epilogue: C/D layout col=lane&15, row=(lane>>4)*4+reg (verified)
    #pragma unroll
    for (int mf = 0; mf < 4; ++mf) {
        #pragma unroll
        for (int reg = 0; reg < 4; ++reg) {
            int o = o0 + wm*64 + mf*16 + (lane >> 4)*4 + reg;
            float bias = bias_all[o];
            __hip_bfloat16* dst; size_t rowbase;
            if (o < 64)       { dst = qb; rowbase = ((size_t)b*NO + o)*NHW; }
            else if (o < 128) { dst = kb; rowbase = ((size_t)b*NO + (o-64))*NHW; }
            else              { dst = vb; rowbase = ((size_t)b*NC + (o-128))*NHW; }
            #pragma unroll
            for (int nf = 0; nf < 4; ++nf) {
                int hw = hw0 + wn*64 + nf*16 + (lane & 15);
                dst[rowbase + hw] = __float2bfloat16(acc[mf][nf][reg] + bias);
            }
        }
    }
}

// K2: generic per-channel 64x64 spatial transpose:
//   dst[b][c][w][i] = src[b][c][i][w]; one c per wave.
__global__ __launch_bounds__(256) void transpose_hw(
    const __hip_bfloat16* __restrict__ src_, __hip_bfloat16* __restrict__ dst_,
    int nch)
{
    __shared__ __align__(16) short tile[4][64*64];
    const int t = threadIdx.x, wv = t >> 6, lane = t & 63;
    const int c = blockIdx.x*4 + wv, b = blockIdx.y;
    const __hip_bfloat16* src = src_ + ((size_t)(b*nch + c))*NHW;
    __hip_bfloat16* dst = dst_ + ((size_t)(b*nch + c))*NHW;
    short* tl = tile[wv];
    #pragma unroll
    for (int s = 0; s < 8; ++s) {
        int i = s*8 + (lane>>3), w0 = (lane&7)*8;
        bf16x8 vv = *(const bf16x8*)(src + i*64 + w0);
        *(bf16x8*)&tl[i*64 + (((w0>>3) ^ ((i>>3)&7)) << 3)] = vv;
    }
    __syncthreads();
    #pragma unroll
    for (int s = 0; s < 8; ++s) {
        int w = s*8 + (lane>>3), i0 = (lane&7)*8;
        bf16x8 ov;
        #pragma unroll
        for (int d = 0; d < 8; ++d)
            ov[d] = tl[(i0+d)*64 + (((w>>3) ^ (lane&7)) << 3) + (w&7)];
        *(bf16x8*)(dst + w*64 + i0) = ov;
    }
}

// K3: scores + softmax, block per (b, h). Column scores read kT (i-contig).
// Emits bf16 attention, k-contiguous: aHb[b][w][h][i], aWb[b][h][w][j]
__global__ __launch_bounds__(256) void scores_softmax(
    const __hip_bfloat16* __restrict__ q, const __hip_bfloat16* __restrict__ k,
    const __hip_bfloat16* __restrict__ kT,
    __hip_bfloat16* __restrict__ aHb, __hip_bfloat16* __restrict__ aWb)
{
    __shared__ float qs[64][65];   // [o][w]
    __shared__ float ksr[64][65];  // [o][j]
    __shared__ float sH[64][65];   // [w][i]
    __shared__ float sW[64][65];   // [w][j]
    __shared__ float red[8][64];
    const int t = threadIdx.x;
    const int w = t & 63, p = t >> 6;
    const int hb = blockIdx.x, b = blockIdx.y;
    #pragma unroll
    for (int s = 0; s < 2; ++s) {
        int idx = s*256 + t;             // 512 octets = 64 o x 8
        int o = idx >> 3, w0 = (idx & 7)*8;
        size_t g = (size_t)(b*NO + o)*NHW + hb*NW + w0;
        bf16x8 qv = *(const bf16x8*)(q + g);
        bf16x8 kv = *(const bf16x8*)(k + g);
        #pragma unroll
        for (int e = 0; e < 8; ++e) {
            qs[o][w0+e]  = bfbits_to_f(qv[e]);
            ksr[o][w0+e] = bfbits_to_f(kv[e]);
        }
    }
    __syncthreads();
    const int ib = p * 16;
    { // column scores: sH[w][ib+ii] = sum_o qs[o][w] * kT[b][o][w][ib+ii]
        float acc[16];
        #pragma unroll
        for (int ii = 0; ii < 16; ++ii) acc[ii] = 0.f;
        const __hip_bfloat16* kp = kT + (size_t)b*NO*NHW + w*64 + ib;
        for (int o = 0; o < 64; ++o) {
            float qv = qs[o][w];
            bf16x8 k0 = *(const bf16x8*)kp;
            bf16x8 k1 = *(const bf16x8*)(kp + 8);
            #pragma unroll
            for (int e = 0; e < 8; ++e) acc[e]   += qv * bfbits_to_f(k0[e]);
            #pragma unroll
            for (int e = 0; e < 8; ++e) acc[8+e] += qv * bfbits_to_f(k1[e]);
            kp += NHW;
        }
        #pragma unroll
        for (int ii = 0; ii < 16; ++ii) sH[w][ib+ii] = acc[ii];
    }
    { // row scores: sW[w][j] = sum_o qs[o][w] * ksr[o][j]
        float acc[16];
        #pragma unroll
        for (int jj = 0; jj < 16; ++jj) acc[jj] = 0.f;
        for (int o = 0; o < 64; ++o) {
            float qv = qs[o][w];
            #pragma unroll
            for (int jj = 0; jj < 16; ++jj) acc[jj] += qv * ksr[o][ib+jj];
        }
        #pragma unroll
        for (int jj = 0; jj < 16; ++jj) sW[w][ib+jj] = acc[jj];
    }
    __syncthreads();
    if (t < 64) sH[t][hb] = -1e30f;   // diag mask i == h
    __syncthreads();
    float m = -1e30f;
    #pragma unroll
    for (int z = 0; z < 32; ++z) {
        float val = (p < 2) ? sH[w][p*32+z] : sW[w][(p-2)*32+z];
        m = fmaxf(m, val);
    }
    red[p][w] = m;
    __syncthreads();
    float M = fmaxf(fmaxf(red[0][w], red[1][w]), fmaxf(red[2][w], red[3][w]));
    float ssum = 0.f;
    #pragma unroll
    for (int z = 0; z < 32; ++z) {
        float* slot = (p < 2) ? &sH[w][p*32+z] : &sW[w][(p-2)*32+z];
        float e = __expf(*slot - M);
        ssum += e;
        *slot = e;
    }
    red[4+p][w] = ssum;
    __syncthreads();
    float S = red[4][w] + red[5][w] + red[6][w] + red[7][w];
    float rinv = 1.f / S;
    if (p < 2) {
        size_t base = (((size_t)b*NH + w)*NH + hb)*NO + p*32;
        #pragma unroll
        for (int zz = 0; zz < 4; ++zz) {
            bf16x8 pk;
            #pragma unroll
            for (int d = 0; d < 8; ++d)
                pk[d] = f2bf_bits(sH[w][p*32 + zz*8 + d] * rinv);
            *(bf16x8*)(aHb + base + zz*8) = pk;
        }
    } else {
        size_t base = (((size_t)b*NH + hb)*NH + w)*NO + (p-2)*32;
        #pragma unroll
        for (int zz = 0; zz < 4; ++zz) {
            bf16x8 pk;
            #pragma unroll
            for (int d = 0; d < 8; ++d)
                pk[d] = f2bf_bits(sW[w][(p-2)*32 + zz*8 + d] * rinv);
            *(bf16x8*)(aWb + base + zz*8) = pk;
        }
    }
}

// K4: col pass MFMA. Block (w, chalf, b): C[h][c] = sum_i aH[h][i] * vT[c][i].
__global__ __launch_bounds__(256) void col_mfma(
    const __hip_bfloat16* __restrict__ vT, const __hip_bfloat16* __restrict__ aH,
    __hip_bfloat16* __restrict__ PT)
{
    __shared__ __align__(16) char As[64*128];    // aH[w]: [h][i]
    __shared__ __align__(16) char Bs[256*128];   // vT: [c][i]
    const int t = threadIdx.x, lane = t & 63, wn = t >> 6;
    const int fr = lane & 15, fg = lane >> 4;
    const int w = blockIdx.x, chalf = blockIdx.y, b = blockIdx.z;
    const __hip_bfloat16* Ag = aH + ((size_t)(b*NH + w))*4096;
    const __hip_bfloat16* Bg = vT + ((size_t)(b*NC + chalf*256))*NHW + w*64;
    #pragma unroll
    for (int s = 0; s < 2; ++s) {
        int linear = s*256 + t;
        int r = linear >> 3, g = linear & 7;
        gload16(Ag + r*64 + ((g ^ (r&7)) * 8), As + linear*16);
    }
    #pragma unroll
    for (int s = 0; s < 8; ++s) {
        int linear = s*256 + t;
        int r = linear >> 3, g = linear & 7;
        gload16(Bg + (size_t)r*NHW + ((g ^ (r&7)) * 8), Bs + linear*16);
    }
    __syncthreads();
    f32x4 acc[4][4] = {};
    #pragma unroll
    for (int kk = 0; kk < 2; ++kk) {
        int gl = kk*4 + fg;
        bf16x8 af[4], bfv[4];
        #pragma unroll
        for (int mf = 0; mf < 4; ++mf) {
            int r = mf*16 + fr;
            af[mf] = *(const bf16x8*)(As + r*128 + ((gl ^ (r&7)) << 4));
        }
        #pragma unroll
        for (int nf = 0; nf < 4; ++nf) {
            int c = wn*64 + nf*16 + fr;
            bfv[nf] = *(const bf16x8*)(Bs + c*128 + ((gl ^ (c&7)) << 4));
        }
        #pragma unroll
        for (int mf = 0; mf < 4; ++mf)
            #pragma unroll
            for (int nf = 0; nf < 4; ++nf)
                acc[mf][nf] = __builtin_amdgcn_mfma_f32_16x16x32_bf16(
                    af[mf], bfv[nf], acc[mf][nf], 0, 0, 0);
    }
    const size_t base = ((size_t)(b*NH + w))*64*512 + chalf*256;
    #pragma unroll
    for (int mf = 0; mf < 4; ++mf) {
        #pragma unroll
        for (int reg = 0; reg < 4; ++reg) {
            int hh = mf*16 + (lane >> 4)*4 + reg;
            #pragma unroll
            for (int nf = 0; nf < 4; ++nf) {
                int cc = wn*64 + nf*16 + (lane & 15);
                PT[base + (size_t)hh*512 + cc] = __float2bfloat16(acc[mf][nf][reg]);
            }
        }
    }
}

// K5: row pass MFMA + PT add + residual. Block (h, cq, b):
//   C[c][w] = sum_j v[c][j] * aW[w][j];  out = gamma*(C + PT^T) + x
__global__ __launch_bounds__(256) void row_mfma(
    const __hip_bfloat16* __restrict__ vb, const __hip_bfloat16* __restrict__ aW,
    const __hip_bfloat16* __restrict__ PT, const float* __restrict__ x,
    const float* __restrict__ gamma, float* __restrict__ out)
{
    __shared__ __align__(16) char Ws[64*128];   // aW[h]: [w][j]
    __shared__ __align__(16) char Vs[128*128];  // v: [c][j]
    __shared__ __align__(16) short PTs[64*136]; // [w][c]
    const int t = threadIdx.x, lane = t & 63, wm = t >> 6;
    const int fr = lane & 15, fg = lane >> 4;
    const int h = blockIdx.x, cq = blockIdx.y, b = blockIdx.z;
    const int c0 = cq*128;
    const __hip_bfloat16* Ag = aW + ((size_t)(b*NH + h))*4096;
    const __hip_bfloat16* Vg = vb + ((size_t)(b*NC + c0))*NHW + h*64;
    #pragma unroll
    for (int s = 0; s < 2; ++s) {
        int linear = s*256 + t;
        int r = linear >> 3, g = linear & 7;
        gload16(Ag + r*64 + ((g ^ (r&7)) * 8), Ws + linear*16);
    }
    #pragma unroll
    for (int s = 0; s < 4; ++s) {
        int linear = s*256 + t;
        int r = linear >> 3, g = linear & 7;
        gload16(Vg + (size_t)r*NHW + ((g ^ (r&7)) * 8), Vs + linear*16);
    }
    #pragma unroll
    for (int s = 0; s < 4; ++s) {
        int idx = s*256 + t;
        int ww = idx >> 4, cg = idx & 15;
        bf16x8 pv = *(const bf16x8*)(PT + (((size_t)(b*NH + ww))*64 + h)*512 + c0 + cg*8);
        *(bf16x8*)&PTs[ww*136 + cg*8] = pv;
    }
    __syncthreads();
    f32x4 acc[2][4] = {};
    #pragma unroll
    for (int kk = 0; kk < 2; ++kk) {
        int gl = kk*4 + fg;
        bf16x8 vf[2], wf[4];
        #pragma unroll
        for (int mf = 0; mf < 2; ++mf) {
            int c = wm*32 + mf*16 + fr;
            vf[mf] = *(const bf16x8*)(Vs + c*128 + ((gl ^ (c&7)) << 4));
        }
        #pragma unroll
        for (int nf = 0; nf < 4; ++nf) {
            int ww = nf*16 + fr;
            wf[nf] = *(const bf16x8*)(Ws + ww*128 + ((gl ^ (ww&7)) << 4));
        }
        #pragma unroll
        for (int mf = 0; mf < 2; ++mf)
            #pragma unroll
            for (int nf = 0; nf < 4; ++nf)
                acc[mf][nf] = __builtin_amdgcn_mfma_f32_16x16x32_bf16(
                    vf[mf], wf[nf], acc[mf][nf], 0, 0, 0);
    }
    const float g = gamma[0];
    #pragma unroll
    for (int mf = 0; mf < 2; ++mf) {
        #pragma unroll
        for (int reg = 0; reg < 4; ++reg) {
            int cl = wm*32 + mf*16 + (lane >> 4)*4 + reg;
            size_t rowbase = ((size_t)(b*NC + c0 + cl)*NH + h)*NW;
            #pragma unroll
            for (int nf = 0; nf < 4; ++nf) {
                int ww = nf*16 + (lane & 15);
                float ptv = bfbits_to_f(PTs[ww*136 + cl]);
                out[rowbase + ww] = g*(acc[mf][nf][reg] + ptv) + x[rowbase + ww];
            }
        }
    }
}

extern "C" void kernel_launch(void* const* d_in, const int* in_sizes, int n_in,
                              void* d_out, int out_size, void* d_ws, size_t ws_size,
                              hipStream_t stream) {
    (void)in_sizes; (void)n_in; (void)out_size; (void)ws_size;
    const float* x     = (const float*)d_in[0];
    const float* Wq    = (const float*)d_in[1];
    const float* bq    = (const float*)d_in[2];
    const float* Wk    = (const float*)d_in[3];
    const float* bk    = (const float*)d_in[4];
    const float* Wv    = (const float*)d_in[5];
    const float* bv    = (const float*)d_in[6];
    const float* gamma = (const float*)d_in[7];
    float* out = (float*)d_out;

    char* p = (char*)d_ws;
    __hip_bfloat16* Wbf = (__hip_bfloat16*)(p);                //    655,360
    float* bias_all     = (float*)(p + 655360);                //      2,560
    __hip_bfloat16* qb  = (__hip_bfloat16*)(p + 657920);       //  4,194,304
    __hip_bfloat16* kb  = (__hip_bfloat16*)(p + 4852224);      //  4,194,304
    __hip_bfloat16* vb  = (__hip_bfloat16*)(p + 9046528);      // 33,554,432
    __hip_bfloat16* xt  = (__hip_bfloat16*)(p + 42600960);     // 33,554,432 (dead after qkv)
    __hip_bfloat16* vT  = (__hip_bfloat16*)(p + 42600960);     //   aliases xt
    __hip_bfloat16* aHb = (__hip_bfloat16*)(p + 76155392);     //  4,194,304
    __hip_bfloat16* aWb = (__hip_bfloat16*)(p + 80349696);     //  4,194,304
    __hip_bfloat16* PT  = (__hip_bfloat16*)(p + 84544000);     // 33,554,432
    __hip_bfloat16* kT  = (__hip_bfloat16*)(p + 118098432);    //  4,194,304
    // total 122,292,736 B

    pack_w<<<dim3(640), 256, 0, stream>>>(Wq, bq, Wk, bk, Wv, bv, Wbf, bias_all);
    transpose_x<<<dim3(8, 64, NB), 256, 0, stream>>>(x, xt);
    qkv_mfma<<<dim3(32, 5, NB), 256, 0, stream>>>(xt, Wbf, bias_all, qb, kb, vb);
    transpose_hw<<<dim3(128, NB), 256, 0, stream>>>(vb, vT, NC);
    transpose_hw<<<dim3(16, NB), 256, 0, stream>>>(kb, kT, NO);
    scores_softmax<<<dim3(NH, NB), 256, 0, stream>>>(qb, kb, kT, aHb, aWb);
    col_mfma<<<dim3(NW, 2, NB), 256, 0, stream>>>(vT, aHb, PT);
    row_mfma<<<dim3(NH, 4, NB), 256, 0, stream>>>(vb, aWb, PT, x, gamma, out);
}

// Round 7
// 121.890 us; speedup vs baseline: 1.2956x; 1.2956x over previous
//
#include <hip/hip_runtime.h>
#include <hip/hip_bf16.h>

#define NB 8
#define NC 512
#define NO 64
#define NH 64
#define NW 64
#define NHW 4096

typedef __attribute__((ext_vector_type(8))) short bf16x8;
typedef __attribute__((ext_vector_type(4))) float f32x4;

__device__ __forceinline__ void gload16(const void* g, void* l) {
    __builtin_amdgcn_global_load_lds(
        (const __attribute__((address_space(1))) void*)g,
        (__attribute__((address_space(3))) void*)l, 16, 0, 0);
}

__device__ __forceinline__ short f2bf_bits(float f) {
    __hip_bfloat16 h = __float2bfloat16(f);
    short s; __builtin_memcpy(&s, &h, 2); return s;
}
__device__ __forceinline__ float bfbits_to_f(short s) {
    unsigned int u = ((unsigned int)(unsigned short)s) << 16;
    float f; __builtin_memcpy(&f, &u, 4); return f;
}

// K0a: pack Wq|Wk|Wv -> Wbf[640][512] bf16, biases -> bias_all[640] f32
__global__ __launch_bounds__(256) void pack_w(
    const float* __restrict__ Wq, const float* __restrict__ bq,
    const float* __restrict__ Wk, const float* __restrict__ bk,
    const float* __restrict__ Wv, const float* __restrict__ bv,
    __hip_bfloat16* __restrict__ Wbf, float* __restrict__ bias_all)
{
    const int row = blockIdx.x;
    const int t = threadIdx.x;
    const float* src; float bias;
    if (row < 64)       { src = Wq + row*NC;        bias = bq[row]; }
    else if (row < 128) { src = Wk + (row-64)*NC;   bias = bk[row-64]; }
    else                { src = Wv + (row-128)*NC;  bias = bv[row-128]; }
    for (int i = t; i < NC; i += 256)
        Wbf[(size_t)row*NC + i] = __float2bfloat16(src[i]);
    if (t == 0) bias_all[row] = bias;
}

// K0b: x[b][c][hw] f32 -> xt[b][hw][c] bf16 (LDS tile transpose)
__global__ __launch_bounds__(256) void transpose_x(
    const float* __restrict__ x, __hip_bfloat16* __restrict__ xt)
{
    __shared__ float tile[64][65];
    const int c0  = blockIdx.x * 64;
    const int hw0 = blockIdx.y * 64;
    const int b   = blockIdx.z;
    const int t = threadIdx.x;
    const int col = t & 63, r4 = t >> 6;
    #pragma unroll
    for (int s = 0; s < 16; ++s) {
        int cr = s*4 + r4;
        tile[cr][col] = x[((size_t)b*NC + c0 + cr)*NHW + hw0 + col];
    }
    __syncthreads();
    #pragma unroll
    for (int s = 0; s < 16; ++s) {
        int wr = s*4 + r4;
        xt[((size_t)b*NHW + hw0 + wr)*NC + c0 + col] = __float2bfloat16(tile[col][wr]);
    }
}

// K1: MFMA QKV projection, double-buffered.
// y<4:  normal orientation, W rows o0s=128+y*128 (all v) -> vb[c][hw]
// y==4: swapped operands (m=hw, n=o over W rows 0..128) -> qkT2[b][hw][128]
__global__ __launch_bounds__(256) void qkv_mfma(
    const __hip_bfloat16* __restrict__ xt, const __hip_bfloat16* __restrict__ Wbf,
    const float* __restrict__ bias_all,
    __hip_bfloat16* __restrict__ qkT2, __hip_bfloat16* __restrict__ vb)
{
    __shared__ __align__(16) char As[2][16384];   // W rows  [128][k64] bf16
    __shared__ __align__(16) char Bs[2][16384];   // xt rows [128][k64] bf16
    const int t = threadIdx.x;
    const int lane = t & 63;
    const int wv = t >> 6;
    const int wm = wv >> 1, wn = wv & 1;
    const int fr = lane & 15, fg = lane >> 4;
    const int hw0 = blockIdx.x * 128;
    const int y   = blockIdx.y;
    const int b   = blockIdx.z;
    const int o0s = (y == 4) ? 0 : (128 + y*128);
    const __hip_bfloat16* xtb = xt + (size_t)b * NHW * NC;

#define STAGE(ksrc, buf)                                                    \
    {                                                                       \
        _Pragma("unroll")                                                   \
        for (int s = 0; s < 4; ++s) {                                       \
            int linear = s*256 + t;                                         \
            int row = linear >> 3, g = linear & 7;                          \
            int gk = (g ^ (row & 7)) * 8;                                   \
            gload16(Wbf + (size_t)(o0s + row)*NC + (ksrc)*64 + gk,          \
                    As[buf] + linear*16);                                   \
            gload16(xtb + (size_t)(hw0 + row)*NC + (ksrc)*64 + gk,          \
                    Bs[buf] + linear*16);                                   \
        }                                                                   \
    }

    STAGE(0, 0);
    __syncthreads();

    f32x4 acc[4][4] = {};

    for (int ks = 0; ks < 8; ++ks) {
        const int cur = ks & 1, nxt = cur ^ 1;
        if (ks < 7) STAGE(ks+1, nxt);
        const char* Ms = (y == 4) ? Bs[cur] : As[cur];  // m-operand rows
        const char* Ns = (y == 4) ? As[cur] : Bs[cur];  // n-operand rows
        #pragma unroll
        for (int kk = 0; kk < 2; ++kk) {
            const int gl = kk*4 + fg;
            bf16x8 m1[4], n1[4];
            #pragma unroll
            for (int mf = 0; mf < 4; ++mf) {
                int r = wm*64 + mf*16 + fr;
                m1[mf] = *(const bf16x8*)(Ms + r*128 + ((gl ^ (r & 7)) << 4));
            }
            #pragma unroll
            for (int nf = 0; nf < 4; ++nf) {
                int c = wn*64 + nf*16 + fr;
                n1[nf] = *(const bf16x8*)(Ns + c*128 + ((gl ^ (c & 7)) << 4));
            }
            #pragma unroll
            for (int mf = 0; mf < 4; ++mf)
                #pragma unroll
                for (int nf = 0; nf < 4; ++nf)
                    acc[mf][nf] = __builtin_amdgcn_mfma_f32_16x16x32_bf16(
                        m1[mf], n1[nf], acc[mf][nf], 0, 0, 0);
        }
        if (ks < 7) __syncthreads();
    }
#undef STAGE

    // C/D layout: col=lane&15 (n-frag), row=(lane>>4)*4+reg (m-frag) — verified
    if (y < 4) {
        #pragma unroll
        for (int mf = 0; mf < 4; ++mf) {
            #pragma unroll
            for (int reg = 0; reg < 4; ++reg) {
                int o = o0s + wm*64 + mf*16 + (lane >> 4)*4 + reg;   // 128..639
                float bias = bias_all[o];
                size_t rowbase = ((size_t)b*NC + (o - 128))*NHW;
                #pragma unroll
                for (int nf = 0; nf < 4; ++nf) {
                    int hw = hw0 + wn*64 + nf*16 + (lane & 15);
                    vb[rowbase + hw] = __float2bfloat16(acc[mf][nf][reg] + bias);
                }
            }
        }
    } else {
        #pragma unroll
        for (int mf = 0; mf < 4; ++mf) {
            #pragma unroll
            for (int reg = 0; reg < 4; ++reg) {
                int hwl = wm*64 + mf*16 + (lane >> 4)*4 + reg;
                size_t rbase = ((size_t)b*NHW + hw0 + hwl)*128;
                #pragma unroll
                for (int nf = 0; nf < 4; ++nf) {
                    int col = wn*64 + nf*16 + (lane & 15);   // 0..127 = q|k
                    qkT2[rbase + col] = __float2bfloat16(acc[mf][nf][reg] + bias_all[col]);
                }
            }
        }
    }
}

// K2: per-channel 64x64 spatial transpose: dst[b][c][w][i] = src[b][c][i][w]
__global__ __launch_bounds__(256) void transpose_hw(
    const __hip_bfloat16* __restrict__ src_, __hip_bfloat16* __restrict__ dst_,
    int nch)
{
    __shared__ __align__(16) short tile[4][64*64];
    const int t = threadIdx.x, wv = t >> 6, lane = t & 63;
    const int c = blockIdx.x*4 + wv, b = blockIdx.y;
    const __hip_bfloat16* src = src_ + ((size_t)(b*nch + c))*NHW;
    __hip_bfloat16* dst = dst_ + ((size_t)(b*nch + c))*NHW;
    short* tl = tile[wv];
    #pragma unroll
    for (int s = 0; s < 8; ++s) {
        int i = s*8 + (lane>>3), w0 = (lane&7)*8;
        bf16x8 vv = *(const bf16x8*)(src + i*64 + w0);
        *(bf16x8*)&tl[i*64 + (((w0>>3) ^ ((i>>3)&7)) << 3)] = vv;
    }
    __syncthreads();
    #pragma unroll
    for (int s = 0; s < 8; ++s) {
        int w = s*8 + (lane>>3), i0 = (lane&7)*8;
        bf16x8 ov;
        #pragma unroll
        for (int d = 0; d < 8; ++d)
            ov[d] = tl[(i0+d)*64 + (((w>>3) ^ (lane&7)) << 3) + (w&7)];
        *(bf16x8*)(dst + w*64 + i0) = ov;
    }
}

// K3a: raw scores via MFMA. Block (s, y, b):
//  y=0: C[h][i] = sum_o q[b,o,h,s]*k[b,o,i,s]   -> rawH[b][s][h][i]
//  y=1: C[w][j] = sum_o q[b,o,s,w]*k[b,o,s,j]   -> rawW[b][s][w][j]
// operands from qkT2[b][hw][0..64)=q, [64..128)=k (o-contiguous)
__global__ __launch_bounds__(256) void scores_mfma(
    const __hip_bfloat16* __restrict__ qkT2,
    __hip_bfloat16* __restrict__ rawH, __hip_bfloat16* __restrict__ rawW)
{
    __shared__ __align__(16) char Qs[64*128];   // [r][o 64] bf16
    __shared__ __align__(16) char Ks[64*128];
    const int t = threadIdx.x, lane = t & 63, wv = t >> 6;
    const int wm = wv >> 1, wn = wv & 1;
    const int fr = lane & 15, fg = lane >> 4;
    const int s = blockIdx.x, y = blockIdx.y, b = blockIdx.z;
    const __hip_bfloat16* base = qkT2 + (size_t)b * NHW * 128;
    #pragma unroll
    for (int i = 0; i < 2; ++i) {
        int linear = i*256 + t;
        int r = linear >> 3, g = linear & 7;
        int gk = (g ^ (r & 7)) * 8;
        size_t ro = (y == 0) ? ((size_t)(r*64 + s) * 128)
                             : ((size_t)(s*64 + r) * 128);
        gload16(base + ro + gk,      Qs + linear*16);
        gload16(base + ro + 64 + gk, Ks + linear*16);
    }
    __syncthreads();
    f32x4 acc[2][2] = {};
    #pragma unroll
    for (int kk = 0; kk < 2; ++kk) {
        const int gl = kk*4 + fg;
        bf16x8 qf[2], kf[2];
        #pragma unroll
        for (int mf = 0; mf < 2; ++mf) {
            int r = wm*32 + mf*16 + fr;
            qf[mf] = *(const bf16x8*)(Qs + r*128 + ((gl ^ (r & 7)) << 4));
        }
        #pragma unroll
        for (int nf = 0; nf < 2; ++nf) {
            int c = wn*32 + nf*16 + fr;
            kf[nf] = *(const bf16x8*)(Ks + c*128 + ((gl ^ (c & 7)) << 4));
        }
        #pragma unroll
        for (int mf = 0; mf < 2; ++mf)
            #pragma unroll
            for (int nf = 0; nf < 2; ++nf)
                acc[mf][nf] = __builtin_amdgcn_mfma_f32_16x16x32_bf16(
                    qf[mf], kf[nf], acc[mf][nf], 0, 0, 0);
    }
    __hip_bfloat16* dst = (y == 0) ? rawH : rawW;
    const size_t dbase = ((size_t)(b*64 + s)) * 4096;
    #pragma unroll
    for (int mf = 0; mf < 2; ++mf) {
        #pragma unroll
        for (int reg = 0; reg < 4; ++reg) {
            int row = wm*32 + mf*16 + (lane >> 4)*4 + reg;
            #pragma unroll
            for (int nf = 0; nf < 2; ++nf) {
                int col = wn*32 + nf*16 + (lane & 15);
                dst[dbase + (size_t)row*64 + col] = __float2bfloat16(acc[mf][nf][reg]);
            }
        }
    }
}

// K3b: softmax over 128 concat logits per pixel. Block (hb, b).
// Reads rawH[b][w][hb][i] (strided) + rawW[b][hb][w][j] (contiguous).
// Emits aHb[b][w][h][i], aWb[b][h][w][j] bf16.
__global__ __launch_bounds__(256) void softmax_ab(
    const __hip_bfloat16* __restrict__ rawH, const __hip_bfloat16* __restrict__ rawW,
    __hip_bfloat16* __restrict__ aHb, __hip_bfloat16* __restrict__ aWb)
{
    __shared__ float sH[64][65];   // [w][i]
    __shared__ float sW[64][65];   // [w][j]
    __shared__ float red[8][64];
    const int t = threadIdx.x;
    const int w = t & 63, p = t >> 6;
    const int hb = blockIdx.x, b = blockIdx.y;
    #pragma unroll
    for (int i2 = 0; i2 < 2; ++i2) {
        int linear = i2*256 + t;
        int ww = linear >> 3, g = linear & 7;
        bf16x8 hv = *(const bf16x8*)(rawH + (((size_t)(b*64 + ww))*64 + hb)*64 + g*8);
        bf16x8 wvv = *(const bf16x8*)(rawW + (((size_t)(b*64 + hb))*64 + ww)*64 + g*8);
        #pragma unroll
        for (int e = 0; e < 8; ++e) {
            sH[ww][g*8+e] = bfbits_to_f(hv[e]);
            sW[ww][g*8+e] = bfbits_to_f(wvv[e]);
        }
    }
    __syncthreads();
    if (t < 64) sH[t][hb] = -1e30f;   // diag mask i == hb
    __syncthreads();
    float m = -1e30f;
    #pragma unroll
    for (int z = 0; z < 32; ++z) {
        float val = (p < 2) ? sH[w][p*32+z] : sW[w][(p-2)*32+z];
        m = fmaxf(m, val);
    }
    red[p][w] = m;
    __syncthreads();
    float M = fmaxf(fmaxf(red[0][w], red[1][w]), fmaxf(red[2][w], red[3][w]));
    float ssum = 0.f;
    #pragma unroll
    for (int z = 0; z < 32; ++z) {
        float* slot = (p < 2) ? &sH[w][p*32+z] : &sW[w][(p-2)*32+z];
        float e = __expf(*slot - M);
        ssum += e;
        *slot = e;
    }
    red[4+p][w] = ssum;
    __syncthreads();
    float S = red[4][w] + red[5][w] + red[6][w] + red[7][w];
    float rinv = 1.f / S;
    if (p < 2) {
        size_t base = (((size_t)b*NH + w)*NH + hb)*NO + p*32;
        #pragma unroll
        for (int zz = 0; zz < 4; ++zz) {
            bf16x8 pk;
            #pragma unroll
            for (int d = 0; d < 8; ++d)
                pk[d] = f2bf_bits(sH[w][p*32 + zz*8 + d] * rinv);
            *(bf16x8*)(aHb + base + zz*8) = pk;
        }
    } else {
        size_t base = (((size_t)b*NH + hb)*NH + w)*NO + (p-2)*32;
        #pragma unroll
        for (int zz = 0; zz < 4; ++zz) {
            bf16x8 pk;
            #pragma unroll
            for (int d = 0; d < 8; ++d)
                pk[d] = f2bf_bits(sW[w][(p-2)*32 + zz*8 + d] * rinv);
            *(bf16x8*)(aWb + base + zz*8) = pk;
        }
    }
}

// K4: col pass MFMA. Block (w, chalf, b): C[h][c] = sum_i aH[h][i] * vT[c][i].
__global__ __launch_bounds__(256) void col_mfma(
    const __hip_bfloat16* __restrict__ vT, const __hip_bfloat16* __restrict__ aH,
    __hip_bfloat16* __restrict__ PT)
{
    __shared__ __align__(16) char As[64*128];    // aH[w]: [h][i]
    __shared__ __align__(16) char Bs[256*128];   // vT: [c][i]
    const int t = threadIdx.x, lane = t & 63, wn = t >> 6;
    const int fr = lane & 15, fg = lane >> 4;
    const int w = blockIdx.x, chalf = blockIdx.y, b = blockIdx.z;
    const __hip_bfloat16* Ag = aH + ((size_t)(b*NH + w))*4096;
    const __hip_bfloat16* Bg = vT + ((size_t)(b*NC + chalf*256))*NHW + w*64;
    #pragma unroll
    for (int s = 0; s < 2; ++s) {
        int linear = s*256 + t;
        int r = linear >> 3, g = linear & 7;
        gload16(Ag + r*64 + ((g ^ (r&7)) * 8), As + linear*16);
    }
    #pragma unroll
    for (int s = 0; s < 8; ++s) {
        int linear = s*256 + t;
        int r = linear >> 3, g = linear & 7;
        gload16(Bg + (size_t)r*NHW + ((g ^ (r&7)) * 8), Bs + linear*16);
    }
    __syncthreads();
    f32x4 acc[4][4] = {};
    #pragma unroll
    for (int kk = 0; kk < 2; ++kk) {
        int gl = kk*4 + fg;
        bf16x8 af[4], bfv[4];
        #pragma unroll
        for (int mf = 0; mf < 4; ++mf) {
            int r = mf*16 + fr;
            af[mf] = *(const bf16x8*)(As + r*128 + ((gl ^ (r&7)) << 4));
        }
        #pragma unroll
        for (int nf = 0; nf < 4; ++nf) {
            int c = wn*64 + nf*16 + fr;
            bfv[nf] = *(const bf16x8*)(Bs + c*128 + ((gl ^ (c&7)) << 4));
        }
        #pragma unroll
        for (int mf = 0; mf < 4; ++mf)
            #pragma unroll
            for (int nf = 0; nf < 4; ++nf)
                acc[mf][nf] = __builtin_amdgcn_mfma_f32_16x16x32_bf16(
                    af[mf], bfv[nf], acc[mf][nf], 0, 0, 0);
    }
    const size_t base = ((size_t)(b*NH + w))*64*512 + chalf*256;
    #pragma unroll
    for (int mf = 0; mf < 4; ++mf) {
        #pragma unroll
        for (int reg = 0; reg < 4; ++reg) {
            int hh = mf*16 + (lane >> 4)*4 + reg;
            #pragma unroll
            for (int nf = 0; nf < 4; ++nf) {
                int cc = wn*64 + nf*16 + (lane & 15);
                PT[base + (size_t)hh*512 + cc] = __float2bfloat16(acc[mf][nf][reg]);
            }
        }
    }
}

// K5: row pass MFMA + PT add + residual. Block (h, cq, b):
//   C[c][w] = sum_j v[c][j] * aW[w][j];  out = gamma*(C + PT^T) + x
__global__ __launch_bounds__(256) void row_mfma(
    const __hip_bfloat16* __restrict__ vb, const __hip_bfloat16* __restrict__ aW,
    const __hip_bfloat16* __restrict__ PT, const float* __restrict__ x,
    const float* __restrict__ gamma, float* __restrict__ out)
{
    __shared__ __align__(16) char Ws[64*128];   // aW[h]: [w][j]
    __shared__ __align__(16) char Vs[128*128];  // v: [c][j]
    __shared__ __align__(16) short PTs[64*136]; // [w][c]
    const int t = threadIdx.x, lane = t & 63, wm = t >> 6;
    const int fr = lane & 15, fg = lane >> 4;
    const int h = blockIdx.x, cq = blockIdx.y, b = blockIdx.z;
    const int c0 = cq*128;
    const __hip_bfloat16* Ag = aW + ((size_t)(b*NH + h))*4096;
    const __hip_bfloat16* Vg = vb + ((size_t)(b*NC + c0))*NHW + h*64;
    #pragma unroll
    for (int s = 0; s < 2; ++s) {
        int linear = s*256 + t;
        int r = linear >> 3, g = linear & 7;
        gload16(Ag + r*64 + ((g ^ (r&7)) * 8), Ws + linear*16);
    }
    #pragma unroll
    for (int s = 0; s < 4; ++s) {
        int linear = s*256 + t;
        int r = linear >> 3, g = linear & 7;
        gload16(Vg + (size_t)r*NHW + ((g ^ (r&7)) * 8), Vs + linear*16);
    }
    #pragma unroll
    for (int s = 0; s < 4; ++s) {
        int idx = s*256 + t;
        int ww = idx >> 4, cg = idx & 15;
        bf16x8 pv = *(const bf16x8*)(PT + (((size_t)(b*NH + ww))*64 + h)*512 + c0 + cg*8);
        *(bf16x8*)&PTs[ww*136 + cg*8] = pv;
    }
    __syncthreads();
    f32x4 acc[2][4] = {};
    #pragma unroll
    for (int kk = 0; kk < 2; ++kk) {
        int gl = kk*4 + fg;
        bf16x8 vf[2], wf[4];
        #pragma unroll
        for (int mf = 0; mf < 2; ++mf) {
            int c = wm*32 + mf*16 + fr;
            vf[mf] = *(const bf16x8*)(Vs + c*128 + ((gl ^ (c&7)) << 4));
        }
        #pragma unroll
        for (int nf = 0; nf < 4; ++nf) {
            int ww = nf*16 + fr;
            wf[nf] = *(const bf16x8*)(Ws + ww*128 + ((gl ^ (ww&7)) << 4));
        }
        #pragma unroll
        for (int mf = 0; mf < 2; ++mf)
            #pragma unroll
            for (int nf = 0; nf < 4; ++nf)
                acc[mf][nf] = __builtin_amdgcn_mfma_f32_16x16x32_bf16(
                    vf[mf], wf[nf], acc[mf][nf], 0, 0, 0);
    }
    const float g = gamma[0];
    #pragma unroll
    for (int mf = 0; mf < 2; ++mf) {
        #pragma unroll
        for (int reg = 0; reg < 4; ++reg) {
            int cl = wm*32 + mf*16 + (lane >> 4)*4 + reg;
            size_t rowbase = ((size_t)(b*NC + c0 + cl)*NH + h)*NW;
            #pragma unroll
            for (int nf = 0; nf < 4; ++nf) {
                int ww = nf*16 + (lane & 15);
                float ptv = bfbits_to_f(PTs[ww*136 + cl]);
                out[rowbase + ww] = g*(acc[mf][nf][reg] + ptv) + x[rowbase + ww];
            }
        }
    }
}

extern "C" void kernel_launch(void* const* d_in, const int* in_sizes, int n_in,
                              void* d_out, int out_size, void* d_ws, size_t ws_size,
                              hipStream_t stream) {
    (void)in_sizes; (void)n_in; (void)out_size; (void)ws_size;
    const float* x     = (const float*)d_in[0];
    const float* Wq    = (const float*)d_in[1];
    const float* bq    = (const float*)d_in[2];
    const float* Wk    = (const float*)d_in[3];
    const float* bk    = (const float*)d_in[4];
    const float* Wv    = (const float*)d_in[5];
    const float* bv    = (const float*)d_in[6];
    const float* gamma = (const float*)d_in[7];
    float* out = (float*)d_out;

    char* p = (char*)d_ws;
    __hip_bfloat16* Wbf  = (__hip_bfloat16*)(p);               //    655,360
    float* bias_all      = (float*)(p + 655360);               //      2,560
    __hip_bfloat16* qkT2 = (__hip_bfloat16*)(p + 657920);      //  8,388,608
    __hip_bfloat16* vb   = (__hip_bfloat16*)(p + 9046528);     // 33,554,432
    __hip_bfloat16* xt   = (__hip_bfloat16*)(p + 42600960);    // 33,554,432 (dead after qkv)
    __hip_bfloat16* vT   = (__hip_bfloat16*)(p + 42600960);    //   aliases xt
    __hip_bfloat16* aHb  = (__hip_bfloat16*)(p + 76155392);    //  4,194,304
    __hip_bfloat16* aWb  = (__hip_bfloat16*)(p + 80349696);    //  4,194,304
    __hip_bfloat16* PT   = (__hip_bfloat16*)(p + 84544000);    // 33,554,432
    // rawH/rawW alias PT (dead before col_mfma writes PT)
    __hip_bfloat16* rawH = PT;                                 //  8,388,608
    __hip_bfloat16* rawW = (__hip_bfloat16*)(p + 84544000 + 8388608);
    // total 118,098,432 B

    pack_w<<<dim3(640), 256, 0, stream>>>(Wq, bq, Wk, bk, Wv, bv, Wbf, bias_all);
    transpose_x<<<dim3(8, 64, NB), 256, 0, stream>>>(x, xt);
    qkv_mfma<<<dim3(32, 5, NB), 256, 0, stream>>>(xt, Wbf, bias_all, qkT2, vb);
    transpose_hw<<<dim3(128, NB), 256, 0, stream>>>(vb, vT, NC);
    scores_mfma<<<dim3(64, 2, NB), 256, 0, stream>>>(qkT2, rawH, rawW);
    softmax_ab<<<dim3(NH, NB), 256, 0, stream>>>(rawH, rawW, aHb, aWb);
    col_mfma<<<dim3(NW, 2, NB), 256, 0, stream>>>(vT, aHb, PT);
    row_mfma<<<dim3(NH, 4, NB), 256, 0, stream>>>(vb, aWb, PT, x, gamma, out);
}